// Round 3
// baseline (4359.838 us; speedup 1.0000x reference)
//
#include <hip/hip_runtime.h>

#define N_TOK 32768
#define EMB_D 256
#define N_EMB 8192
#define TM 128
#define KC 256
#define DC 32
#define NDC (EMB_D / DC)   // 8
#define NKC (N_EMB / KC)   // 32

// ---------------- Kernel A: half-norms of codebook rows (+ zero loss slot) ---
__global__ __launch_bounds__(256) void vq_norms(const float* __restrict__ cb,
                                                float* __restrict__ hnorm,
                                                float* __restrict__ out) {
    int tid = threadIdx.x;
    int k = blockIdx.x * 4 + (tid >> 6);   // one wave (64 lanes) per code row
    int lane = tid & 63;
    const float4* row = (const float4*)(cb + (size_t)k * EMB_D);
    float4 v = row[lane];                  // 64 lanes x float4 = 256 elems
    float s = v.x * v.x + v.y * v.y + v.z * v.z + v.w * v.w;
#pragma unroll
    for (int off = 1; off < 64; off <<= 1) s += __shfl_xor(s, off);
    if (lane == 0) hnorm[k] = 0.5f * s;
    if (blockIdx.x == 0 && tid == 0) out[(size_t)N_TOK * EMB_D] = 0.0f;
}

// ---------------- Kernel B: tiled score GEMM + argmin ----------------------
// score(n,k) = 0.5*||e_k||^2 - x_n . e_k   (argmin-equivalent to L2 distance)
__global__ __launch_bounds__(512) void vq_argmin(const float* __restrict__ x,
                                                 const float* __restrict__ cb,
                                                 const float* __restrict__ hnorm,
                                                 int* __restrict__ idx_out) {
    // transposed LDS tiles: d-major so inner loop reads codes with ds_read_b128
    __shared__ __align__(16) float xs[DC][TM + 4];   // stride 132 words (528B, 16B-aligned)
    __shared__ __align__(16) float es[DC][KC + 4];   // stride 260 words (1040B, 16B-aligned)
    __shared__ float hn_s[KC];

    int tid = threadIdx.x;
    int ty = tid >> 5;   // 0..15 -> token group (8 tokens)
    int tx = tid & 31;   // 0..31 -> code group (8 codes)
    int row0 = blockIdx.x * TM;

    float best[8];
    int   bidx[8];
#pragma unroll
    for (int i = 0; i < 8; ++i) { best[i] = 3.0e38f; bidx[i] = 0; }

    for (int kc = 0; kc < NKC; ++kc) {
        int k0 = kc * KC;
        __syncthreads();                       // protect hn_s reuse from prev iter
        if (tid < KC) hn_s[tid] = hnorm[k0 + tid];

        float acc[8][8];
#pragma unroll
        for (int i = 0; i < 8; ++i)
#pragma unroll
            for (int j = 0; j < 8; ++j) acc[i][j] = 0.0f;

        for (int dc = 0; dc < NDC; ++dc) {
            int d0 = dc * DC;
            // stage x tile transposed: 128 rows x 32 d = 1024 float4 loads
#pragma unroll
            for (int q = 0; q < 2; ++q) {
                int lin = tid + q * 512;
                int r = lin >> 3, c = lin & 7;
                float4 v = *(const float4*)(x + (size_t)(row0 + r) * EMB_D + d0 + c * 4);
                xs[c * 4 + 0][r] = v.x; xs[c * 4 + 1][r] = v.y;
                xs[c * 4 + 2][r] = v.z; xs[c * 4 + 3][r] = v.w;
            }
            // stage codebook tile transposed: 256 rows x 32 d = 2048 float4 loads
#pragma unroll
            for (int q = 0; q < 4; ++q) {
                int lin = tid + q * 512;
                int r = lin >> 3, c = lin & 7;
                float4 v = *(const float4*)(cb + (size_t)(k0 + r) * EMB_D + d0 + c * 4);
                es[c * 4 + 0][r] = v.x; es[c * 4 + 1][r] = v.y;
                es[c * 4 + 2][r] = v.z; es[c * 4 + 3][r] = v.w;
            }
            __syncthreads();
#pragma unroll 4
            for (int d = 0; d < DC; ++d) {
                float4 e0 = *(const float4*)&es[d][tx * 8];
                float4 e1 = *(const float4*)&es[d][tx * 8 + 4];
                float er[8] = {e0.x, e0.y, e0.z, e0.w, e1.x, e1.y, e1.z, e1.w};
                float xr[8];
#pragma unroll
                for (int i = 0; i < 8; ++i) xr[i] = xs[d][ty * 8 + i];
#pragma unroll
                for (int i = 0; i < 8; ++i)
#pragma unroll
                    for (int j = 0; j < 8; ++j)
                        acc[i][j] = fmaf(xr[i], er[j], acc[i][j]);
            }
            __syncthreads();
        }
        // fold this code chunk into the running per-thread argmin
#pragma unroll
        for (int j = 0; j < 8; ++j) {
            float hn = hn_s[tx * 8 + j];
            int k = k0 + tx * 8 + j;
#pragma unroll
            for (int i = 0; i < 8; ++i) {
                float s = hn - acc[i][j];
                if (s < best[i]) { best[i] = s; bidx[i] = k; }  // strict <: first-min
            }
        }
    }
    // cross-lane argmin across tx (lex order (score, idx) -> matches jnp.argmin)
#pragma unroll
    for (int off = 16; off >= 1; off >>= 1) {
#pragma unroll
        for (int i = 0; i < 8; ++i) {
            float os = __shfl_xor(best[i], off);
            int   ok = __shfl_xor(bidx[i], off);
            if (os < best[i] || (os == best[i] && ok < bidx[i])) {
                best[i] = os; bidx[i] = ok;
            }
        }
    }
    if (tx == 0) {
#pragma unroll
        for (int i = 0; i < 8; ++i) idx_out[row0 + ty * 8 + i] = bidx[i];
    }
}

// ---------------- Kernel C: gather quantized rows + loss -------------------
__global__ __launch_bounds__(256) void vq_gather(const float* __restrict__ x,
                                                 const float* __restrict__ cb,
                                                 const int* __restrict__ idx,
                                                 float* __restrict__ out) {
    int tid = threadIdx.x;
    int t0 = blockIdx.x * 64;
    float lsum = 0.f;
    for (int tt = 0; tt < 64; ++tt) {
        int t = t0 + tt;
        int k = idx[t];
        float q  = cb[(size_t)k * EMB_D + tid];
        float xv = x[(size_t)t * EMB_D + tid];
        out[(size_t)t * EMB_D + tid] = q;
        float dq = q - xv;
        lsum = fmaf(dq, dq, lsum);
    }
#pragma unroll
    for (int off = 1; off < 64; off <<= 1) lsum += __shfl_xor(lsum, off);
    __shared__ float red[4];
    int lane = tid & 63, w = tid >> 6;
    if (lane == 0) red[w] = lsum;
    __syncthreads();
    if (tid == 0) {
        float s = red[0] + red[1] + red[2] + red[3];
        // loss = (1.0 + 0.25) * mean((q - x)^2)
        atomicAdd(out + (size_t)N_TOK * EMB_D, s * (1.25f / (float)((size_t)N_TOK * EMB_D)));
    }
}

extern "C" void kernel_launch(void* const* d_in, const int* in_sizes, int n_in,
                              void* d_out, int out_size, void* d_ws, size_t ws_size,
                              hipStream_t stream) {
    const float* x  = (const float*)d_in[0];
    const float* cb = (const float*)d_in[1];
    float* out = (float*)d_out;
    float* hnorm = (float*)d_ws;
    int* idx = (int*)((char*)d_ws + (size_t)N_EMB * sizeof(float));

    vq_norms<<<N_EMB / 4, 256, 0, stream>>>(cb, hnorm, out);
    vq_argmin<<<N_TOK / TM, 512, 0, stream>>>(x, cb, hnorm, idx);
    vq_gather<<<N_TOK / 64, 256, 0, stream>>>(x, cb, idx, out);
}

// Round 6
// 2143.681 us; speedup vs baseline: 2.0338x; 2.0338x over previous
//
#include <hip/hip_runtime.h>

#define N_TOK 32768
#define EMB_D 256
#define N_EMB 8192
#define TM 128
#define KC 256
#define DC 32
#define NDC (EMB_D / DC)   // 8
#define NKC (N_EMB / KC)   // 32

// ---------------- Kernel A: half-norms of codebook rows (+ zero loss slot) ---
__global__ __launch_bounds__(256) void vq_norms(const float* __restrict__ cb,
                                                float* __restrict__ hnorm,
                                                float* __restrict__ out) {
    int tid = threadIdx.x;
    int k = blockIdx.x * 4 + (tid >> 6);   // one wave (64 lanes) per code row
    int lane = tid & 63;
    const float4* row = (const float4*)(cb + (size_t)k * EMB_D);
    float4 v = row[lane];                  // 64 lanes x float4 = 256 elems
    float s = v.x * v.x + v.y * v.y + v.z * v.z + v.w * v.w;
#pragma unroll
    for (int off = 1; off < 64; off <<= 1) s += __shfl_xor(s, off);
    if (lane == 0) hnorm[k] = 0.5f * s;
    if (blockIdx.x == 0 && tid == 0) out[(size_t)N_TOK * EMB_D] = 0.0f;
}

// ---------------- Kernel B: tiled score GEMM + argmin ----------------------
// score(n,k) = 0.5*||e_k||^2 - x_n . e_k   (argmin-equivalent to L2 distance)
// Lane (ty,tx) owns tokens ty*8..+7 and codes {tx*4..+3} u {128+tx*4..+3}
// within each 256-code chunk -> all LDS inner-loop reads are contiguous b128
// (conflict-free) or same-address broadcast.
__global__ __launch_bounds__(512) void vq_argmin(const float* __restrict__ x,
                                                 const float* __restrict__ cb,
                                                 const float* __restrict__ hnorm,
                                                 int* __restrict__ idx_out) {
    __shared__ __align__(16) float xs[DC][TM + 4];   // stride 132 words (528B = 33*16)
    __shared__ __align__(16) float es[DC][KC + 4];   // stride 260 words (1040B = 65*16)
    __shared__ float hn_s[KC];

    int tid = threadIdx.x;
    int ty = tid >> 5;   // 0..15 -> token group (8 tokens)
    int tx = tid & 31;   // 0..31 -> code group (4 + 4 codes)
    int row0 = blockIdx.x * TM;

    float best[8];
    int   bidx[8];
#pragma unroll
    for (int i = 0; i < 8; ++i) { best[i] = 3.0e38f; bidx[i] = 0; }

    for (int kc = 0; kc < NKC; ++kc) {
        int k0 = kc * KC;
        __syncthreads();                       // protect hn_s reuse from prev iter
        if (tid < KC) hn_s[tid] = hnorm[k0 + tid];

        float acc[8][8];
#pragma unroll
        for (int i = 0; i < 8; ++i)
#pragma unroll
            for (int j = 0; j < 8; ++j) acc[i][j] = 0.0f;

        for (int dc = 0; dc < NDC; ++dc) {
            int d0 = dc * DC;
            // stage x tile transposed: 128 rows x 32 d
#pragma unroll
            for (int q = 0; q < 2; ++q) {
                int lin = tid + q * 512;
                int r = lin >> 3, c = lin & 7;
                float4 v = *(const float4*)(x + (size_t)(row0 + r) * EMB_D + d0 + c * 4);
                xs[c * 4 + 0][r] = v.x; xs[c * 4 + 1][r] = v.y;
                xs[c * 4 + 2][r] = v.z; xs[c * 4 + 3][r] = v.w;
            }
            // stage codebook tile transposed: 256 rows x 32 d
#pragma unroll
            for (int q = 0; q < 4; ++q) {
                int lin = tid + q * 512;
                int r = lin >> 3, c = lin & 7;
                float4 v = *(const float4*)(cb + (size_t)(k0 + r) * EMB_D + d0 + c * 4);
                es[c * 4 + 0][r] = v.x; es[c * 4 + 1][r] = v.y;
                es[c * 4 + 2][r] = v.z; es[c * 4 + 3][r] = v.w;
            }
            __syncthreads();
#pragma unroll 4
            for (int d = 0; d < DC; ++d) {
                // codes: 32 lanes x 16B contiguous per read -> conflict-free
                float4 e0 = *(const float4*)&es[d][tx * 4];          // codes tx*4..+3
                float4 e1 = *(const float4*)&es[d][128 + tx * 4];    // codes 128+tx*4..+3
                float er[8] = {e0.x, e0.y, e0.z, e0.w, e1.x, e1.y, e1.z, e1.w};
                // tokens: same-address broadcast across the 32 tx lanes
                float4 x0 = *(const float4*)&xs[d][ty * 8];
                float4 x1 = *(const float4*)&xs[d][ty * 8 + 4];
                float xr[8] = {x0.x, x0.y, x0.z, x0.w, x1.x, x1.y, x1.z, x1.w};
#pragma unroll
                for (int i = 0; i < 8; ++i)
#pragma unroll
                    for (int j = 0; j < 8; ++j)
                        acc[i][j] = fmaf(xr[i], er[j], acc[i][j]);
            }
            __syncthreads();
        }
        // fold this code chunk into the running per-thread argmin
        // (j ascending => k ascending within thread: first-min semantics hold)
#pragma unroll
        for (int j = 0; j < 8; ++j) {
            int kk = (j < 4) ? (tx * 4 + j) : (128 + tx * 4 + (j - 4));
            float hn = hn_s[kk];
            int k = k0 + kk;
#pragma unroll
            for (int i = 0; i < 8; ++i) {
                float s = hn - acc[i][j];
                if (s < best[i]) { best[i] = s; bidx[i] = k; }  // strict <: first-min
            }
        }
    }
    // cross-lane argmin across tx (lex order (score, idx) -> matches jnp.argmin)
#pragma unroll
    for (int off = 16; off >= 1; off >>= 1) {
#pragma unroll
        for (int i = 0; i < 8; ++i) {
            float os = __shfl_xor(best[i], off);
            int   ok = __shfl_xor(bidx[i], off);
            if (os < best[i] || (os == best[i] && ok < bidx[i])) {
                best[i] = os; bidx[i] = ok;
            }
        }
    }
    if (tx == 0) {
#pragma unroll
        for (int i = 0; i < 8; ++i) idx_out[row0 + ty * 8 + i] = bidx[i];
    }
}

// ---------------- Kernel C: gather quantized rows + loss -------------------
__global__ __launch_bounds__(256) void vq_gather(const float* __restrict__ x,
                                                 const float* __restrict__ cb,
                                                 const int* __restrict__ idx,
                                                 float* __restrict__ out) {
    int tid = threadIdx.x;
    int t0 = blockIdx.x * 64;
    float lsum = 0.f;
    for (int tt = 0; tt < 64; ++tt) {
        int t = t0 + tt;
        int k = idx[t];
        float q  = cb[(size_t)k * EMB_D + tid];
        float xv = x[(size_t)t * EMB_D + tid];
        out[(size_t)t * EMB_D + tid] = q;
        float dq = q - xv;
        lsum = fmaf(dq, dq, lsum);
    }
#pragma unroll
    for (int off = 1; off < 64; off <<= 1) lsum += __shfl_xor(lsum, off);
    __shared__ float red[4];
    int lane = tid & 63, w = tid >> 6;
    if (lane == 0) red[w] = lsum;
    __syncthreads();
    if (tid == 0) {
        float s = red[0] + red[1] + red[2] + red[3];
        // loss = (1.0 + 0.25) * mean((q - x)^2)
        atomicAdd(out + (size_t)N_TOK * EMB_D, s * (1.25f / (float)((size_t)N_TOK * EMB_D)));
    }
}

extern "C" void kernel_launch(void* const* d_in, const int* in_sizes, int n_in,
                              void* d_out, int out_size, void* d_ws, size_t ws_size,
                              hipStream_t stream) {
    const float* x  = (const float*)d_in[0];
    const float* cb = (const float*)d_in[1];
    float* out = (float*)d_out;
    float* hnorm = (float*)d_ws;
    int* idx = (int*)((char*)d_ws + (size_t)N_EMB * sizeof(float));

    vq_norms<<<N_EMB / 4, 256, 0, stream>>>(cb, hnorm, out);
    vq_argmin<<<N_TOK / TM, 512, 0, stream>>>(x, cb, hnorm, idx);
    vq_gather<<<N_TOK / 64, 256, 0, stream>>>(x, cb, idx, out);
}

// Round 8
// 977.498 us; speedup vs baseline: 4.4602x; 2.1930x over previous
//
#include <hip/hip_runtime.h>

#define N_TOK 32768
#define EMB_D 256
#define N_EMB 8192
#define TM 128          // tokens per score block
#define CHUNK 256       // codes per kc chunk
#define KS 32           // dims per dc slice
#define NKC (N_EMB / CHUNK)   // 32
#define NDC (EMB_D / KS)      // 8

typedef __attribute__((ext_vector_type(8))) short short8;
typedef __attribute__((ext_vector_type(4))) float f32x4;
typedef __attribute__((ext_vector_type(4))) unsigned int uint4v;
typedef unsigned short ushort_t;

// ---- LDS layout for vq_score (dynamic, 77824 B) ----
#define XA_OFF(p) ((p) * 8192)            // 3 x-planes: [128 rows][64 B]
#define EA_OFF(p) (24576 + (p) * 16384)   // 3 e-planes: [256 rows][64 B]
#define FIN_OFF   73728                   // u64 fin[128][4]
#define SMEM_BYTES 77824

// ---- ws layout (bytes); requires ws_size >= ~63.3 MB ----
// xp[3]  @ 0,        each 16,777,216
// ep[3]  @ 50331648, each  4,194,304
// nh     @ 62914560  (8192 f32, negated half-norms)
// cand   @ 62947328  (32768 i32)
// idxf   @ 63078400  (32768 i32)

__device__ __forceinline__ ushort_t rne_bf16(float f) {
    unsigned u = __float_as_uint(f);
    return (ushort_t)((u + 0x7FFFu + ((u >> 16) & 1u)) >> 16);
}
__device__ __forceinline__ float bf16_to_f32(ushort_t h) {
    return __uint_as_float(((unsigned)h) << 16);
}

// ---------------- split a f32 array into 3 bf16 planes ----------------------
__global__ __launch_bounds__(256) void vq_split(const float* __restrict__ src,
                                                ushort_t* __restrict__ p0,
                                                ushort_t* __restrict__ p1,
                                                ushort_t* __restrict__ p2) {
    size_t i = (size_t)blockIdx.x * 256 + threadIdx.x;   // float4 index
    float4 v = *(const float4*)(src + i * 4);
    float vv[4] = {v.x, v.y, v.z, v.w};
    ushort_t h[4], m[4], l[4];
#pragma unroll
    for (int j = 0; j < 4; ++j) {
        ushort_t hh = rne_bf16(vv[j]);
        float r = vv[j] - bf16_to_f32(hh);      // exact (Sterbenz)
        ushort_t mm = rne_bf16(r);
        float r2 = r - bf16_to_f32(mm);         // exact
        h[j] = hh; m[j] = mm; l[j] = rne_bf16(r2);
    }
    *(ushort4*)(p0 + i * 4) = make_ushort4(h[0], h[1], h[2], h[3]);
    *(ushort4*)(p1 + i * 4) = make_ushort4(m[0], m[1], m[2], m[3]);
    *(ushort4*)(p2 + i * 4) = make_ushort4(l[0], l[1], l[2], l[3]);
}

// ---------------- negated half-norms + zero loss slot -----------------------
__global__ __launch_bounds__(256) void vq_norms(const float* __restrict__ cb,
                                                float* __restrict__ nh,
                                                float* __restrict__ out) {
    int tid = threadIdx.x;
    int k = blockIdx.x * 4 + (tid >> 6);
    int lane = tid & 63;
    float4 v = ((const float4*)(cb + (size_t)k * EMB_D))[lane];
    float s = v.x * v.x + v.y * v.y + v.z * v.z + v.w * v.w;
#pragma unroll
    for (int off = 1; off < 64; off <<= 1) s += __shfl_xor(s, off);
    if (lane == 0) nh[k] = -0.5f * s;
    if (blockIdx.x == 0 && tid == 0) out[(size_t)N_TOK * EMB_D] = 0.0f;
}

// ---------------- MFMA 6-pass score + coarse argmax -------------------------
// maximize s'(t,k) = x_t.e_k - 0.5||e_k||^2  (equiv to min L2 distance)
__global__ __launch_bounds__(512, 2) void vq_score(
    const ushort_t* __restrict__ xp0, const ushort_t* __restrict__ xp1,
    const ushort_t* __restrict__ xp2, const ushort_t* __restrict__ ep0,
    const ushort_t* __restrict__ ep1, const ushort_t* __restrict__ ep2,
    const float* __restrict__ nh, int* __restrict__ cand) {
    extern __shared__ char smem[];
    unsigned long long* fin = (unsigned long long*)(smem + FIN_OFF);

    const int tid = threadIdx.x;
    const int lane = tid & 63;
    const int wid = tid >> 6;
    const int wm = wid >> 2;     // 0..1: token half (64 rows)
    const int wn = wid & 3;      // 0..3: code quarter (64 codes)
    const int l15 = lane & 15;
    const int lg = lane >> 4;    // k-group 0..3
    const int row0 = blockIdx.x * TM;

    const ushort_t* xplanes[3] = {xp0, xp1, xp2};
    const ushort_t* eplanes[3] = {ep0, ep1, ep2};

    float run[16];
    float tagf[16];
#pragma unroll
    for (int s = 0; s < 16; ++s) { run[s] = -3.0e38f; tagf[s] = 0.0f; }

    for (int kc = 0; kc < NKC; ++kc) {
        const int k0 = kc * CHUNK;
        f32x4 acc[4][4];
#pragma unroll
        for (int m = 0; m < 4; ++m)
#pragma unroll
            for (int n = 0; n < 4; ++n) acc[m][n] = (f32x4)0.0f;

        for (int dc = 0; dc < NDC; ++dc) {
            __syncthreads();   // previous slice fully consumed
            // stage x (q 0..2) and e (q 3..8) 16B chunks, XOR-swizzled rows
#pragma unroll
            for (int q = 0; q < 9; ++q) {
                int lin = tid + q * 512;
                const ushort_t* src;
                int ldsbyte;
                if (q < 3) {
                    int p = lin >> 9, rem = lin & 511;
                    int row = rem >> 2, gs = rem & 3;
                    int g = gs ^ ((row >> 1) & 3);
                    src = xplanes[p] + (size_t)(row0 + row) * EMB_D + dc * KS + g * 8;
                    ldsbyte = XA_OFF(p) + row * 64 + gs * 16;
                } else {
                    int l2 = lin - 1536;
                    int p = l2 >> 10, rem = l2 & 1023;
                    int row = rem >> 2, gs = rem & 3;
                    int g = gs ^ ((row >> 1) & 3);
                    src = eplanes[p] + (size_t)(k0 + row) * EMB_D + dc * KS + g * 8;
                    ldsbyte = EA_OFF(p) + row * 64 + gs * 16;
                }
                *(uint4v*)(smem + ldsbyte) = *(const uint4v*)src;
            }
            __syncthreads();

            // A fragments: token rows, 3 planes
            short8 a[4][3];
#pragma unroll
            for (int m = 0; m < 4; ++m) {
                int row = wm * 64 + m * 16 + l15;
                int gsw = lg ^ ((row >> 1) & 3);
#pragma unroll
                for (int p = 0; p < 3; ++p)
                    a[m][p] = *(const short8*)(smem + XA_OFF(p) + row * 64 + gsw * 16);
            }
            // B fragments per n, then 6-pass MFMA into acc
#pragma unroll
            for (int n = 0; n < 4; ++n) {
                int row = wn * 64 + n * 16 + l15;
                int gsw = lg ^ ((row >> 1) & 3);
                short8 b0 = *(const short8*)(smem + EA_OFF(0) + row * 64 + gsw * 16);
                short8 b1 = *(const short8*)(smem + EA_OFF(1) + row * 64 + gsw * 16);
                short8 b2 = *(const short8*)(smem + EA_OFF(2) + row * 64 + gsw * 16);
#pragma unroll
                for (int m = 0; m < 4; ++m) {
                    acc[m][n] = __builtin_amdgcn_mfma_f32_16x16x32_bf16(a[m][0], b0, acc[m][n], 0, 0, 0);
                    acc[m][n] = __builtin_amdgcn_mfma_f32_16x16x32_bf16(a[m][0], b1, acc[m][n], 0, 0, 0);
                    acc[m][n] = __builtin_amdgcn_mfma_f32_16x16x32_bf16(a[m][1], b0, acc[m][n], 0, 0, 0);
                    acc[m][n] = __builtin_amdgcn_mfma_f32_16x16x32_bf16(a[m][0], b2, acc[m][n], 0, 0, 0);
                    acc[m][n] = __builtin_amdgcn_mfma_f32_16x16x32_bf16(a[m][1], b1, acc[m][n], 0, 0, 0);
                    acc[m][n] = __builtin_amdgcn_mfma_f32_16x16x32_bf16(a[m][2], b0, acc[m][n], 0, 0, 0);
                }
            }
        }
        // fold chunk into per-slot running max + kc tag
        float nhv[4];
#pragma unroll
        for (int n = 0; n < 4; ++n) nhv[n] = nh[k0 + wn * 64 + n * 16 + l15];
        float kcf = (float)kc;
#pragma unroll
        for (int m = 0; m < 4; ++m)
#pragma unroll
            for (int r = 0; r < 4; ++r) {
                float s = acc[m][0][r] + nhv[0];
                s = fmaxf(s, acc[m][1][r] + nhv[1]);
                s = fmaxf(s, acc[m][2][r] + nhv[2]);
                s = fmaxf(s, acc[m][3][r] + nhv[3]);
                int slot = m * 4 + r;
                bool upd = s > run[slot];            // strict >: first chunk wins ties
                run[slot] = upd ? s : run[slot];
                tagf[slot] = upd ? kcf : tagf[slot];
            }
    }

    // final: per-slot cross-lane (16-group) argmax with packed (score, meta)
#pragma unroll
    for (int s = 0; s < 16; ++s) {
        unsigned u = __float_as_uint(run[s]);
        unsigned ord = (u & 0x80000000u) ? ~u : (u | 0x80000000u);  // monotone map
        unsigned tag = (unsigned)tagf[s];
        unsigned meta = 0x1FFu ^ ((tag << 4) | (unsigned)l15);      // larger = smaller code
        unsigned long long key = ((unsigned long long)ord << 32) | meta;
#pragma unroll
        for (int off = 1; off <= 8; off <<= 1) {
            unsigned long long o = __shfl_xor(key, off);
            if (o > key) key = o;
        }
        if (l15 == s) {
            int m = s >> 2, r = s & 3;
            int token = wm * 64 + m * 16 + lg * 4 + r;
            fin[token * 4 + wn] = key;
        }
    }
    __syncthreads();
    if (tid < TM) {
        unsigned long long best = fin[tid * 4];
        int bwn = 0;
#pragma unroll
        for (int w = 1; w < 4; ++w) {
            unsigned long long v = fin[tid * 4 + w];
            if (v > best) { best = v; bwn = w; }    // strict >: smaller wn (code) on tie
        }
        unsigned raw = 0x1FFu ^ ((unsigned)best & 0x1FFu);
        int tag = (int)(raw >> 4), ln4 = (int)(raw & 15u);
        cand[row0 + tid] = tag * CHUNK + bwn * 64 + ln4;   // + nf*16 resolved later
    }
}

// ---------------- resolve 4 candidates per token in f32 ---------------------
__global__ __launch_bounds__(512) void vq_resolve(const float* __restrict__ x,
                                                  const float* __restrict__ cb,
                                                  const float* __restrict__ nh,
                                                  const int* __restrict__ cand,
                                                  int* __restrict__ idxf) {
    int wid = threadIdx.x >> 6, lane = threadIdx.x & 63;
    int t = blockIdx.x * 8 + wid;
    float4 xv = *(const float4*)(x + (size_t)t * EMB_D + lane * 4);
    int base = cand[t];
    float s[4];
#pragma unroll
    for (int nf = 0; nf < 4; ++nf) {
        float4 ev = *(const float4*)(cb + (size_t)(base + nf * 16) * EMB_D + lane * 4);
        float d = xv.x * ev.x + xv.y * ev.y + xv.z * ev.z + xv.w * ev.w;
#pragma unroll
        for (int off = 1; off < 64; off <<= 1) d += __shfl_xor(d, off);
        s[nf] = d + nh[base + nf * 16];
    }
    if (lane == 0) {
        float best = s[0];
        int bc = base;
#pragma unroll
        for (int nf = 1; nf < 4; ++nf)
            if (s[nf] > best) { best = s[nf]; bc = base + nf * 16; }  // strict >: smaller code on tie
        idxf[t] = bc;
    }
}

// ---------------- gather quantized rows + loss ------------------------------
__global__ __launch_bounds__(256) void vq_gather(const float* __restrict__ x,
                                                 const float* __restrict__ cb,
                                                 const int* __restrict__ idxf,
                                                 float* __restrict__ out) {
    int tid = threadIdx.x;
    int t0 = blockIdx.x * 64;
    float lsum = 0.f;
    for (int tt = 0; tt < 64; ++tt) {
        int t = t0 + tt;
        int k = idxf[t];
        float q = cb[(size_t)k * EMB_D + tid];
        float xv = x[(size_t)t * EMB_D + tid];
        out[(size_t)t * EMB_D + tid] = q;
        float dq = q - xv;
        lsum = fmaf(dq, dq, lsum);
    }
#pragma unroll
    for (int off = 1; off < 64; off <<= 1) lsum += __shfl_xor(lsum, off);
    __shared__ float red[4];
    int lane = tid & 63, w = tid >> 6;
    if (lane == 0) red[w] = lsum;
    __syncthreads();
    if (tid == 0) {
        float ssum = red[0] + red[1] + red[2] + red[3];
        atomicAdd(out + (size_t)N_TOK * EMB_D,
                  ssum * (1.25f / (float)((size_t)N_TOK * EMB_D)));
    }
}

extern "C" void kernel_launch(void* const* d_in, const int* in_sizes, int n_in,
                              void* d_out, int out_size, void* d_ws, size_t ws_size,
                              hipStream_t stream) {
    const float* x = (const float*)d_in[0];
    const float* cb = (const float*)d_in[1];
    float* out = (float*)d_out;

    char* ws = (char*)d_ws;
    ushort_t* xp0 = (ushort_t*)(ws);
    ushort_t* xp1 = (ushort_t*)(ws + 16777216);
    ushort_t* xp2 = (ushort_t*)(ws + 33554432);
    ushort_t* ep0 = (ushort_t*)(ws + 50331648);
    ushort_t* ep1 = (ushort_t*)(ws + 54525952);
    ushort_t* ep2 = (ushort_t*)(ws + 58720256);
    float* nh     = (float*)(ws + 62914560);
    int* cand     = (int*)(ws + 62947328);
    int* idxf     = (int*)(ws + 63078400);

    vq_split<<<(N_TOK * EMB_D / 4) / 256, 256, 0, stream>>>(x, xp0, xp1, xp2);
    vq_split<<<(N_EMB * EMB_D / 4) / 256, 256, 0, stream>>>(cb, ep0, ep1, ep2);
    vq_norms<<<N_EMB / 4, 256, 0, stream>>>(cb, nh, out);

    hipFuncSetAttribute((const void*)vq_score,
                        hipFuncAttributeMaxDynamicSharedMemorySize, SMEM_BYTES);
    vq_score<<<N_TOK / TM, 512, SMEM_BYTES, stream>>>(xp0, xp1, xp2, ep0, ep1, ep2,
                                                      nh, cand);
    vq_resolve<<<N_TOK / 8, 512, 0, stream>>>(x, cb, nh, cand, idxf);
    vq_gather<<<N_TOK / 64, 256, 0, stream>>>(x, cb, idxf, out);
}

// Round 10
// 694.326 us; speedup vs baseline: 6.2792x; 1.4078x over previous
//
#include <hip/hip_runtime.h>

#define N_TOK 32768
#define EMB_D 256
#define N_EMB 8192
#define TM 128          // tokens per score block
#define CHUNK 256       // codes per kc chunk
#define KS 32           // dims per dc slice
#define NKC (N_EMB / CHUNK)   // 32
#define NDC (EMB_D / KS)      // 8
#define NSLICE (NKC * NDC)    // 256

typedef __attribute__((ext_vector_type(8))) short short8;
typedef __attribute__((ext_vector_type(4))) float f32x4;
typedef unsigned short ushort_t;
typedef __attribute__((address_space(3))) unsigned int lds_uint;
typedef const __attribute__((address_space(1))) unsigned int gbl_uint;

// ---- LDS layout for vq_score (dynamic, 151552 B) ----
// two slice buffers (73728 B each): per buffer 3 x-planes [128][64B] then
// 3 e-planes [256][64B]; fin[128][4] u64 at the end.
#define BUF_BYTES 73728
#define XA_OFF(p) ((p) * 8192)
#define EA_OFF(p) (24576 + (p) * 16384)
#define FIN_OFF   147456
#define SMEM_BYTES 151552

// ---- ws layout (bytes); requires ws_size >= ~63.3 MB ----
__device__ __forceinline__ ushort_t rne_bf16(float f) {
    unsigned u = __float_as_uint(f);
    return (ushort_t)((u + 0x7FFFu + ((u >> 16) & 1u)) >> 16);
}
__device__ __forceinline__ float bf16_to_f32(ushort_t h) {
    return __uint_as_float(((unsigned)h) << 16);
}

// ---------------- split a f32 array into 3 bf16 planes ----------------------
__global__ __launch_bounds__(256) void vq_split(const float* __restrict__ src,
                                                ushort_t* __restrict__ p0,
                                                ushort_t* __restrict__ p1,
                                                ushort_t* __restrict__ p2) {
    size_t i = (size_t)blockIdx.x * 256 + threadIdx.x;   // float4 index
    float4 v = *(const float4*)(src + i * 4);
    float vv[4] = {v.x, v.y, v.z, v.w};
    ushort_t h[4], m[4], l[4];
#pragma unroll
    for (int j = 0; j < 4; ++j) {
        ushort_t hh = rne_bf16(vv[j]);
        float r = vv[j] - bf16_to_f32(hh);      // exact (Sterbenz)
        ushort_t mm = rne_bf16(r);
        float r2 = r - bf16_to_f32(mm);         // exact
        h[j] = hh; m[j] = mm; l[j] = rne_bf16(r2);
    }
    *(ushort4*)(p0 + i * 4) = make_ushort4(h[0], h[1], h[2], h[3]);
    *(ushort4*)(p1 + i * 4) = make_ushort4(m[0], m[1], m[2], m[3]);
    *(ushort4*)(p2 + i * 4) = make_ushort4(l[0], l[1], l[2], l[3]);
}

// ---------------- negated half-norms + zero loss slot -----------------------
__global__ __launch_bounds__(256) void vq_norms(const float* __restrict__ cb,
                                                float* __restrict__ nh,
                                                float* __restrict__ out) {
    int tid = threadIdx.x;
    int k = blockIdx.x * 4 + (tid >> 6);
    int lane = tid & 63;
    float4 v = ((const float4*)(cb + (size_t)k * EMB_D))[lane];
    float s = v.x * v.x + v.y * v.y + v.z * v.z + v.w * v.w;
#pragma unroll
    for (int off = 1; off < 64; off <<= 1) s += __shfl_xor(s, off);
    if (lane == 0) nh[k] = -0.5f * s;
    if (blockIdx.x == 0 && tid == 0) out[(size_t)N_TOK * EMB_D] = 0.0f;
}

// ---------------- MFMA 6-pass score + coarse argmax -------------------------
// maximize s'(t,k) = x_t.e_k - 0.5||e_k||^2  (equiv to min L2 distance)
// 2-phase pipeline: STAGE(next slice -> other buffer) via global_load_lds,
// then MFMA on current buffer, then ONE __syncthreads per slice (compiler
// emits the vmcnt(0) drain there).
__global__ __launch_bounds__(512, 2) void vq_score(
    const ushort_t* __restrict__ xp0, const ushort_t* __restrict__ xp1,
    const ushort_t* __restrict__ xp2, const ushort_t* __restrict__ ep0,
    const ushort_t* __restrict__ ep1, const ushort_t* __restrict__ ep2,
    const float* __restrict__ nh, int* __restrict__ cand) {
    extern __shared__ char smem[];
    unsigned long long* fin = (unsigned long long*)(smem + FIN_OFF);

    const int tid = threadIdx.x;
    const int lane = tid & 63;
    const int wid = tid >> 6;
    const int wm = wid >> 2;     // 0..1: token half (64 rows)
    const int wn = wid & 3;      // 0..3: code quarter (64 codes)
    const int l15 = lane & 15;
    const int lg = lane >> 4;    // k-group 0..3
    const int row0 = blockIdx.x * TM;

    const ushort_t* xplanes[3] = {xp0, xp1, xp2};
    const ushort_t* eplanes[3] = {ep0, ep1, ep2};

    // stage slice t (kc = t>>3, dc = t&7) into buffer b. Per wave the LDS
    // destination is wave-uniform + lane*16 (global_load_lds contract);
    // the XOR row-swizzle is applied on the GLOBAL source side (m173).
    auto STAGE = [&](int t, int b) {
        const int kcs = t >> 3, dcs = t & 7;
        const int kk0 = kcs * CHUNK;
        char* base = smem + b * BUF_BYTES;
#pragma unroll
        for (int q = 0; q < 9; ++q) {
            int lin = tid + q * 512;
            const ushort_t* src;
            int ldsbyte;
            if (q < 3) {
                int p = lin >> 9, rem = lin & 511;
                int row = rem >> 2, gs = rem & 3;
                int g = gs ^ ((row >> 1) & 3);
                src = xplanes[p] + (size_t)(row0 + row) * EMB_D + dcs * KS + g * 8;
                ldsbyte = XA_OFF(p) + row * 64 + gs * 16;
            } else {
                int l2 = lin - 1536;
                int p = l2 >> 10, rem = l2 & 1023;
                int row = rem >> 2, gs = rem & 3;
                int g = gs ^ ((row >> 1) & 3);
                src = eplanes[p] + (size_t)(kk0 + row) * EMB_D + dcs * KS + g * 8;
                ldsbyte = EA_OFF(p) + row * 64 + gs * 16;
            }
            __builtin_amdgcn_global_load_lds((gbl_uint*)src,
                                             (lds_uint*)(base + ldsbyte), 16, 0, 0);
        }
    };

    float run[16];
    float tagf[16];
#pragma unroll
    for (int s = 0; s < 16; ++s) { run[s] = -3.0e38f; tagf[s] = 0.0f; }

    STAGE(0, 0);
    __syncthreads();          // drains vmcnt(0): buf0 ready
    int cur = 0;

    for (int kc = 0; kc < NKC; ++kc) {
        const int k0 = kc * CHUNK;
        f32x4 acc[4][4];
#pragma unroll
        for (int m = 0; m < 4; ++m)
#pragma unroll
            for (int n = 0; n < 4; ++n) acc[m][n] = (f32x4)0.0f;

        for (int dc = 0; dc < NDC; ++dc) {
            const int t = kc * NDC + dc;
            if (t + 1 < NSLICE) STAGE(t + 1, cur ^ 1);   // prefetch next slice

            char* base = smem + cur * BUF_BYTES;
            // A fragments: token rows, 3 planes
            short8 a[4][3];
#pragma unroll
            for (int m = 0; m < 4; ++m) {
                int row = wm * 64 + m * 16 + l15;
                int gsw = lg ^ ((row >> 1) & 3);
#pragma unroll
                for (int p = 0; p < 3; ++p)
                    a[m][p] = *(const short8*)(base + XA_OFF(p) + row * 64 + gsw * 16);
            }
            // B fragments per n, then 6-pass MFMA into acc
#pragma unroll
            for (int n = 0; n < 4; ++n) {
                int row = wn * 64 + n * 16 + l15;
                int gsw = lg ^ ((row >> 1) & 3);
                short8 b0 = *(const short8*)(base + EA_OFF(0) + row * 64 + gsw * 16);
                short8 b1 = *(const short8*)(base + EA_OFF(1) + row * 64 + gsw * 16);
                short8 b2 = *(const short8*)(base + EA_OFF(2) + row * 64 + gsw * 16);
#pragma unroll
                for (int m = 0; m < 4; ++m) {
                    acc[m][n] = __builtin_amdgcn_mfma_f32_16x16x32_bf16(a[m][0], b0, acc[m][n], 0, 0, 0);
                    acc[m][n] = __builtin_amdgcn_mfma_f32_16x16x32_bf16(a[m][0], b1, acc[m][n], 0, 0, 0);
                    acc[m][n] = __builtin_amdgcn_mfma_f32_16x16x32_bf16(a[m][1], b0, acc[m][n], 0, 0, 0);
                    acc[m][n] = __builtin_amdgcn_mfma_f32_16x16x32_bf16(a[m][0], b2, acc[m][n], 0, 0, 0);
                    acc[m][n] = __builtin_amdgcn_mfma_f32_16x16x32_bf16(a[m][1], b1, acc[m][n], 0, 0, 0);
                    acc[m][n] = __builtin_amdgcn_mfma_f32_16x16x32_bf16(a[m][2], b0, acc[m][n], 0, 0, 0);
                }
            }
            // one barrier per slice: compiler emits s_waitcnt vmcnt(0) lgkmcnt(0)
            // here, which (a) lands the prefetch into buf[cur^1] and (b) ensures
            // all waves are done reading buf[cur] before it is re-staged.
            __syncthreads();
            cur ^= 1;
        }
        // fold chunk into per-slot running max + kc tag
        float nhv[4];
#pragma unroll
        for (int n = 0; n < 4; ++n) nhv[n] = nh[k0 + wn * 64 + n * 16 + l15];
        float kcf = (float)kc;
#pragma unroll
        for (int m = 0; m < 4; ++m)
#pragma unroll
            for (int r = 0; r < 4; ++r) {
                float s = acc[m][0][r] + nhv[0];
                s = fmaxf(s, acc[m][1][r] + nhv[1]);
                s = fmaxf(s, acc[m][2][r] + nhv[2]);
                s = fmaxf(s, acc[m][3][r] + nhv[3]);
                int slot = m * 4 + r;
                bool upd = s > run[slot];            // strict >: first chunk wins ties
                run[slot] = upd ? s : run[slot];
                tagf[slot] = upd ? kcf : tagf[slot];
            }
    }

    // final: per-slot cross-lane (16-group) argmax with packed (score, meta)
#pragma unroll
    for (int s = 0; s < 16; ++s) {
        unsigned u = __float_as_uint(run[s]);
        unsigned ord = (u & 0x80000000u) ? ~u : (u | 0x80000000u);  // monotone map
        unsigned tag = (unsigned)tagf[s];
        unsigned meta = 0x1FFu ^ ((tag << 4) | (unsigned)l15);      // larger = smaller code
        unsigned long long key = ((unsigned long long)ord << 32) | meta;
#pragma unroll
        for (int off = 1; off <= 8; off <<= 1) {
            unsigned long long o = __shfl_xor(key, off);
            if (o > key) key = o;
        }
        if (l15 == s) {
            int m = s >> 2, r = s & 3;
            int token = wm * 64 + m * 16 + lg * 4 + r;
            fin[token * 4 + wn] = key;
        }
    }
    __syncthreads();
    if (tid < TM) {
        unsigned long long best = fin[tid * 4];
        int bwn = 0;
#pragma unroll
        for (int w = 1; w < 4; ++w) {
            unsigned long long v = fin[tid * 4 + w];
            if (v > best) { best = v; bwn = w; }    // strict >: smaller wn (code) on tie
        }
        unsigned raw = 0x1FFu ^ ((unsigned)best & 0x1FFu);
        int tag = (int)(raw >> 4), ln4 = (int)(raw & 15u);
        cand[row0 + tid] = tag * CHUNK + bwn * 64 + ln4;   // + nf*16 resolved later
    }
}

// ---------------- resolve 4 candidates per token in f32 ---------------------
__global__ __launch_bounds__(512) void vq_resolve(const float* __restrict__ x,
                                                  const float* __restrict__ cb,
                                                  const float* __restrict__ nh,
                                                  const int* __restrict__ cand,
                                                  int* __restrict__ idxf) {
    int wid = threadIdx.x >> 6, lane = threadIdx.x & 63;
    int t = blockIdx.x * 8 + wid;
    float4 xv = *(const float4*)(x + (size_t)t * EMB_D + lane * 4);
    int base = cand[t];
    float s[4];
#pragma unroll
    for (int nf = 0; nf < 4; ++nf) {
        float4 ev = *(const float4*)(cb + (size_t)(base + nf * 16) * EMB_D + lane * 4);
        float d = xv.x * ev.x + xv.y * ev.y + xv.z * ev.z + xv.w * ev.w;
#pragma unroll
        for (int off = 1; off < 64; off <<= 1) d += __shfl_xor(d, off);
        s[nf] = d + nh[base + nf * 16];
    }
    if (lane == 0) {
        float best = s[0];
        int bc = base;
#pragma unroll
        for (int nf = 1; nf < 4; ++nf)
            if (s[nf] > best) { best = s[nf]; bc = base + nf * 16; }  // strict >: smaller code on tie
        idxf[t] = bc;
    }
}

// ---------------- gather quantized rows + loss ------------------------------
__global__ __launch_bounds__(256) void vq_gather(const float* __restrict__ x,
                                                 const float* __restrict__ cb,
                                                 const int* __restrict__ idxf,
                                                 float* __restrict__ out) {
    int tid = threadIdx.x;
    int t0 = blockIdx.x * 64;
    float lsum = 0.f;
    for (int tt = 0; tt < 64; ++tt) {
        int t = t0 + tt;
        int k = idxf[t];
        float q = cb[(size_t)k * EMB_D + tid];
        float xv = x[(size_t)t * EMB_D + tid];
        out[(size_t)t * EMB_D + tid] = q;
        float dq = q - xv;
        lsum = fmaf(dq, dq, lsum);
    }
#pragma unroll
    for (int off = 1; off < 64; off <<= 1) lsum += __shfl_xor(lsum, off);
    __shared__ float red[4];
    int lane = tid & 63, w = tid >> 6;
    if (lane == 0) red[w] = lsum;
    __syncthreads();
    if (tid == 0) {
        float ssum = red[0] + red[1] + red[2] + red[3];
        atomicAdd(out + (size_t)N_TOK * EMB_D,
                  ssum * (1.25f / (float)((size_t)N_TOK * EMB_D)));
    }
}

extern "C" void kernel_launch(void* const* d_in, const int* in_sizes, int n_in,
                              void* d_out, int out_size, void* d_ws, size_t ws_size,
                              hipStream_t stream) {
    const float* x = (const float*)d_in[0];
    const float* cb = (const float*)d_in[1];
    float* out = (float*)d_out;

    char* ws = (char*)d_ws;
    ushort_t* xp0 = (ushort_t*)(ws);
    ushort_t* xp1 = (ushort_t*)(ws + 16777216);
    ushort_t* xp2 = (ushort_t*)(ws + 33554432);
    ushort_t* ep0 = (ushort_t*)(ws + 50331648);
    ushort_t* ep1 = (ushort_t*)(ws + 54525952);
    ushort_t* ep2 = (ushort_t*)(ws + 58720256);
    float* nh     = (float*)(ws + 62914560);
    int* cand     = (int*)(ws + 62947328);
    int* idxf     = (int*)(ws + 63078400);

    vq_split<<<(N_TOK * EMB_D / 4) / 256, 256, 0, stream>>>(x, xp0, xp1, xp2);
    vq_split<<<(N_EMB * EMB_D / 4) / 256, 256, 0, stream>>>(cb, ep0, ep1, ep2);
    vq_norms<<<N_EMB / 4, 256, 0, stream>>>(cb, nh, out);

    hipFuncSetAttribute((const void*)vq_score,
                        hipFuncAttributeMaxDynamicSharedMemorySize, SMEM_BYTES);
    vq_score<<<N_TOK / TM, 512, SMEM_BYTES, stream>>>(xp0, xp1, xp2, ep0, ep1, ep2,
                                                      nh, cand);
    vq_resolve<<<N_TOK / 8, 512, 0, stream>>>(x, cb, nh, cand, idxf);
    vq_gather<<<N_TOK / 64, 256, 0, stream>>>(x, cb, idxf, out);
}